// Round 6
// baseline (295.201 us; speedup 1.0000x reference)
//
#include <hip/hip_runtime.h>

// Problem constants
#define BB    2
#define HN    8
#define NSEQ  2048
#define DIMM  1536
#define DKD   64
#define DVD   192
#define QCOLS 512        // HN*DKD
#define VCOLS 1536       // HN*DVD

typedef short short8 __attribute__((ext_vector_type(8)));
typedef float f32x4  __attribute__((ext_vector_type(4)));
typedef unsigned short ushortT;

static __device__ inline ushortT f2bf(float f) {
    unsigned u = __builtin_bit_cast(unsigned, f);
    u = (u + 0x7FFFu + ((u >> 16) & 1u)) >> 16;
    return (ushortT)u;
}

// async global -> LDS, 16B per lane. LDS dest = wave-uniform base + lane*16.
static __device__ inline void gl_lds16(const ushortT* g, ushortT* l) {
    __builtin_amdgcn_global_load_lds(
        (const __attribute__((address_space(1))) unsigned int*)g,
        (__attribute__((address_space(3))) unsigned int*)l, 16, 0, 0);
}

// HW waitcnt + COMPILER memory fence in one.
#define FENCE_VM0()    asm volatile("s_waitcnt vmcnt(0)" ::: "memory")
#define FENCE_VM3()    asm volatile("s_waitcnt vmcnt(3)" ::: "memory")
#define FENCE_VM12()   asm volatile("s_waitcnt vmcnt(12)" ::: "memory")
#define FENCE_LGKM0()  asm volatile("s_waitcnt lgkmcnt(0)" ::: "memory")
#define FENCE_SOFT()   asm volatile("" ::: "memory")

// ---------------------------------------------------------------------------
// Prep (single launch): region-decoded by blockIdx.x  (unchanged)
// ---------------------------------------------------------------------------
__global__ __launch_bounds__(256)
void prep_kernel(const float* __restrict__ x,
                 const float* __restrict__ Wq, const float* __restrict__ Wk,
                 const float* __restrict__ Wv, const float* __restrict__ Wo,
                 ushortT* __restrict__ xb, ushortT* __restrict__ wqkv,
                 ushortT* __restrict__ wo_t)
{
    __shared__ ushortT tt[32][33];
    const int b = blockIdx.x, tid = threadIdx.x;

    if (b < 3072) {
        const size_t idx = (size_t)b * 256 + tid;
        const float4* p = (const float4*)x + idx * 2;
        const float4 a = p[0], c = p[1];
        short8 v;
        v[0] = f2bf(a.x); v[1] = f2bf(a.y); v[2] = f2bf(a.z); v[3] = f2bf(a.w);
        v[4] = f2bf(c.x); v[5] = f2bf(c.y); v[6] = f2bf(c.z); v[7] = f2bf(c.w);
        *(short8*)(xb + idx * 8) = v;
        return;
    }

    const float* W; ushortT* Wt; int ncols, t;
    if (b < 3840)      { W = Wq; Wt = wqkv;                          ncols = QCOLS; t = b - 3072; }
    else if (b < 4608) { W = Wk; Wt = wqkv + (size_t)QCOLS * DIMM;   ncols = QCOLS; t = b - 3840; }
    else if (b < 6912) { W = Wv; Wt = wqkv + (size_t)2*QCOLS * DIMM; ncols = VCOLS; t = b - 4608; }
    else               { W = Wo; Wt = wo_t;                          ncols = DIMM;  t = b - 6912; }

    const int nbx = ncols >> 5;
    const int c0 = (t % nbx) * 32, k0 = (t / nbx) * 32;
    const int lx = tid & 31, ly = tid >> 5;
    #pragma unroll
    for (int r = 0; r < 4; r++)
        tt[ly + r * 8][lx] = f2bf(W[(size_t)(k0 + ly + r * 8) * ncols + c0 + lx]);
    __syncthreads();
    #pragma unroll
    for (int r = 0; r < 4; r++)
        Wt[(size_t)(c0 + ly + r * 8) * DIMM + k0 + lx] = tt[lx][ly + r * 8];
}

// ---------------------------------------------------------------------------
// GEMM (R6): BM=128, BN=64, BK=32; 4 waves, acc[2][4]; THREE LDS buffers,
// 2-round lookahead, counted vmcnt(3) + raw s_barrier (never drain to 0 in
// the steady-state loop). Round t: stage S(t+2) (3 gl_lds/wave) -> ds_read
// + 8 MFMA on tile t -> vmcnt(3) (S(t+1) landed, S(t+2) in flight) ->
// s_barrier. Loads get 2 rounds to cover L2 latency. LDS 36 KB -> 4
// blocks/CU = 16 waves/CU. Correctness of raw barrier: each wave's ds_reads
// retire before its MFMAs issue (register deps), so by barrier time all
// reads of the to-be-overwritten buffer are done; per-wave vmcnt(3)
// collectively guarantees the next tile is resident.
// v_ws key-slot permutation (R5): key n -> slot 2*(n&15)|((n>>4)&1) within
// each 32-group; matches flash's packed P-store order.
// ---------------------------------------------------------------------------
#define BKG   32
#define NKT3  (DIMM / BKG)   // 48 rounds

__global__ __launch_bounds__(256)
void gemm_kernel(const ushortT* __restrict__ A, const ushortT* __restrict__ Bt,
                 const float* __restrict__ bo,
                 const float* __restrict__ pos, const float* __restrict__ rcb,
                 ushortT* __restrict__ q_ws, ushortT* __restrict__ k_ws,
                 ushortT* __restrict__ v_ws, float* __restrict__ Cout, int mode)
{
    __shared__ ushortT As[3][128 * BKG];   // 3 x 8 KB
    __shared__ ushortT Bs[3][64 * BKG];    // 3 x 4 KB

    const int tid  = threadIdx.x;
    const int wave = tid >> 6, lane = tid & 63;
    const int quad = lane >> 4, l15 = lane & 15;
    const int m0 = blockIdx.y * 128, n0 = blockIdx.x * 64;

    // staging source swizzle: 16 rows x 4 chunks of 8 shorts per gl_lds
    const int sl_r = lane >> 2;                       // 0..15
    const int sl_c = ((lane & 3) ^ (sl_r & 3)) * 8;   // XOR-swizzled col chunk

    const ushortT* Ab = A  + (size_t)m0 * DIMM;
    const ushortT* Bb = Bt + (size_t)n0 * DIMM;

    f32x4 acc[2][4];
    #pragma unroll
    for (int i = 0; i < 2; i++)
        #pragma unroll
        for (int j = 0; j < 4; j++) acc[i][j] = (f32x4){0.f, 0.f, 0.f, 0.f};

    // stage K-step t into buffer t%3: 2 A-groups + 1 B-group per wave
    auto STAGE = [&](int t) {
        const int k0 = t * BKG;
        const int bf3 = t % 3;
        #pragma unroll
        for (int u = 0; u < 2; u++) {
            const int g = wave * 2 + u;               // 8 groups of 16 rows
            gl_lds16(Ab + (size_t)(g * 16 + sl_r) * DIMM + k0 + sl_c, &As[bf3][g * 512]);
        }
        gl_lds16(Bb + (size_t)(wave * 16 + sl_r) * DIMM + k0 + sl_c, &Bs[bf3][wave * 512]);
    };

    // prologue: 2 tiles in flight, wait for the first
    STAGE(0);
    STAGE(1);
    FENCE_VM3();                      // S0 landed; S1 in flight
    __builtin_amdgcn_s_barrier();

    for (int kt = 0; kt < NKT3; kt++) {
        if (kt + 2 < NKT3) STAGE(kt + 2);

        const int bf3 = kt % 3;
        short8 af[2], bf[4];
        #pragma unroll
        for (int i = 0; i < 2; i++) {
            const int r = wave * 32 + i * 16 + l15;
            af[i] = *(const short8*)&As[bf3][r * BKG + ((quad ^ (r & 3)) * 8)];
        }
        #pragma unroll
        for (int j = 0; j < 4; j++) {
            const int r = j * 16 + l15;
            bf[j] = *(const short8*)&Bs[bf3][r * BKG + ((quad ^ (r & 3)) * 8)];
        }

        #pragma unroll
        for (int i = 0; i < 2; i++)
            #pragma unroll
            for (int j = 0; j < 4; j++)
                acc[i][j] = __builtin_amdgcn_mfma_f32_16x16x32_bf16(af[i], bf[j], acc[i][j], 0, 0, 0);

        if (kt + 2 < NKT3)      { FENCE_VM3(); }   // S(kt+1) landed, S(kt+2) in flight
        else if (kt + 1 < NKT3) { FENCE_VM0(); }   // last staged tile must land
        __builtin_amdgcn_s_barrier();
    }

    #pragma unroll
    for (int i = 0; i < 2; i++) {
        #pragma unroll
        for (int j = 0; j < 4; j++) {
            const int gcol = n0 + j * 16 + l15;
            #pragma unroll
            for (int r = 0; r < 4; r++) {
                const int grow = m0 + wave * 32 + i * 16 + quad * 4 + r;
                const float val = acc[i][j][r];
                if (mode == 1) {
                    Cout[(size_t)grow * DIMM + gcol] = val + bo[gcol];
                } else {
                    const int b = grow >> 11, n = grow & (NSEQ - 1);
                    if (gcol < QCOLS) {
                        const int h = gcol >> 6, d = gcol & 63;
                        q_ws[((size_t)(b * HN + h) * NSEQ + n) * DKD + d] =
                            f2bf(val * 0.125f + pos[((size_t)h * NSEQ + n) * DKD + d] + rcb[h * DKD + d]);
                    } else if (gcol < 2 * QCOLS) {
                        const int c = gcol - QCOLS, h = c >> 6, d = c & 63;
                        k_ws[((size_t)(b * HN + h) * NSEQ + n) * DKD + d] = f2bf(val);
                    } else {
                        const int c = gcol - 2 * QCOLS, h = c / DVD, d = c - h * DVD;
                        // interleaved key-slot within each 32-key group
                        const int p = (n & ~31) | (((n & 15) << 1) | ((n >> 4) & 1));
                        v_ws[((size_t)(b * HN + h) * DVD + d) * NSEQ + p] = f2bf(val);   // [b,h,d,slot]
                    }
                }
            }
        }
    }
}

// ---------------------------------------------------------------------------
// Flash v2c + packed P-store (unchanged from R5).
// Grid 1024 = 16 bh (XCD-affine) x 64 q-tiles of 32 rows. Block = 2 waves.
// Wave w: keys [w*1024, +1024), KT=32, 32 rounds, PRIVATE 16KB K/V staging;
// per-wave self-sync: lgkm0 -> stage K(4)+V(12) -> vmcnt(12) -> QK/softmax/P
// -> vmcnt(0) -> PV. Key-half partials combined via one LDS exchange at end.
// Packed P: lane holds both nt=0/nt=1 values of each P-row; interleaved
// v_ws key slots (2*l15+nt) let them pack into one v_cvt_pk_bf16_f32 +
// one ds_write_b32.
// ---------------------------------------------------------------------------
#define PLD2 40
#define SHIFT 20.0f

__global__ __launch_bounds__(128)
void flash_kernel(const ushortT* __restrict__ q_ws, const ushortT* __restrict__ k_ws,
                  const ushortT* __restrict__ v_ws, ushortT* __restrict__ attn)
{
    // [0,16384): per-wave staging (wave*8192: K 2048 shorts, V 6144 shorts)
    // [16384,18944): P buffers (wave*32*PLD2); reused for l exchange at end
    __shared__ ushortT lds[16384 + 2 * 32 * PLD2];

    const int tid = threadIdx.x;
    const int wave = tid >> 6, lane = tid & 63;
    const int quad = lane >> 4, l15 = lane & 15;

    const int bh = blockIdx.x & 15;        // XCD-affine: bh's blocks share L2
    const int qt = blockIdx.x >> 4;
    const int n0 = qt * 32;
    const int b  = bh >> 3, h = bh & 7;

    const ushortT* kg = k_ws + (size_t)bh * NSEQ * DKD + (size_t)(wave * 1024) * DKD;
    const ushortT* vg = v_ws + (size_t)bh * DVD * NSEQ + wave * 1024;

    ushortT* st = lds + wave * 8192;           // K at [0,2048), V at [2048,8192)
    ushortT* Pw = lds + 16384 + wave * (32 * PLD2);

    // staging source swizzles
    const int k_r = lane >> 3, k_c = ((lane & 7) ^ (k_r & 7)) * 8;   // K: 8 rows x 8 chunks
    const int v_r = lane >> 2, v_c = ((lane & 3) ^ (v_r & 3)) * 8;   // V: 16 rows x 4 chunks

    // Q A-frags (resident): qf[mt][ks], rows n0 + mt*16 + l15
    short8 qf[2][2];
    #pragma unroll
    for (int mt = 0; mt < 2; mt++)
        #pragma unroll
        for (int ks = 0; ks < 2; ks++)
            qf[mt][ks] = *(const short8*)(q_ws + ((size_t)bh * NSEQ + n0 + mt * 16 + l15) * DKD + ks * 32 + quad * 8);

    f32x4 o[2][12];
    #pragma unroll
    for (int mt = 0; mt < 2; mt++)
        #pragma unroll
        for (int nt = 0; nt < 12; nt++) o[mt][nt] = (f32x4){0.f, 0.f, 0.f, 0.f};

    float l_part[2][4];
    #pragma unroll
    for (int mt = 0; mt < 2; mt++)
        #pragma unroll
        for (int i = 0; i < 4; i++) l_part[mt][i] = 0.f;

    for (int kt0 = 0; kt0 < 1024; kt0 += 32) {
        // all prior ds_reads on this wave's buffers must be retired
        FENCE_LGKM0();

        #pragma unroll
        for (int t = 0; t < 4; t++)       // K tile: 32 keys x 64 d = 4 KB
            gl_lds16(kg + (size_t)(kt0 + t * 8 + k_r) * DKD + k_c, st + t * 512);
        #pragma unroll
        for (int u = 0; u < 12; u++)      // V^T tile: 192 d x 32 key-slots = 12 KB
            gl_lds16(vg + (size_t)(u * 16 + v_r) * NSEQ + kt0 + v_c, st + 2048 + u * 512);

        FENCE_VM12();  // 4 oldest (K) landed; V still in flight

        // ---- S = Q @ K^T ----
        f32x4 s[2][2];
        #pragma unroll
        for (int mt = 0; mt < 2; mt++)
            #pragma unroll
            for (int nt = 0; nt < 2; nt++) s[mt][nt] = (f32x4){0.f, 0.f, 0.f, 0.f};
        #pragma unroll
        for (int ks = 0; ks < 2; ks++)
            #pragma unroll
            for (int nt = 0; nt < 2; nt++) {
                const int key = nt * 16 + l15;
                short8 kf = *(const short8*)&st[key * 64 + (((ks * 4 + quad) ^ (key & 7)) * 8)];
                s[0][nt] = __builtin_amdgcn_mfma_f32_16x16x32_bf16(qf[0][ks], kf, s[0][nt], 0, 0, 0);
                s[1][nt] = __builtin_amdgcn_mfma_f32_16x16x32_bf16(qf[1][ks], kf, s[1][nt], 0, 0, 0);
            }

        // ---- p = exp(s - SHIFT); row-sum partials; PACKED P store ----
        // lane holds keys l15 (nt=0) and l15+16 (nt=1) of row mt*16+quad*4+i;
        // interleaved slots (2*l15, 2*l15+1) -> one cvt_pk + one b32 write.
        #pragma unroll
        for (int mt = 0; mt < 2; mt++)
            #pragma unroll
            for (int i = 0; i < 4; i++) {
                const float p0 = __expf(s[mt][0][i] - SHIFT);
                const float p1 = __expf(s[mt][1][i] - SHIFT);
                l_part[mt][i] += p0 + p1;
                unsigned pk;
                asm("v_cvt_pk_bf16_f32 %0, %1, %2" : "=v"(pk) : "v"(p0), "v"(p1));
                *(unsigned*)&Pw[(mt * 16 + quad * 4 + i) * PLD2 + 2 * l15] = pk;
            }

        FENCE_SOFT();  // cross-lane P write->read dep is invisible per-lane

        short8 a[2];
        #pragma unroll
        for (int mt = 0; mt < 2; mt++)
            a[mt] = *(const short8*)&Pw[(mt * 16 + l15) * PLD2 + quad * 8];

        FENCE_VM0();   // V landed

        // ---- O += P @ V (k-slots permuted identically on both operands) ----
        #pragma unroll
        for (int nt2 = 0; nt2 < 12; nt2++) {
            const int d = nt2 * 16 + l15;
            short8 vf = *(const short8*)&st[2048 + d * 32 + ((quad ^ (d & 3)) * 8)];
            o[0][nt2] = __builtin_amdgcn_mfma_f32_16x16x32_bf16(a[0], vf, o[0][nt2], 0, 0, 0);
            o[1][nt2] = __builtin_amdgcn_mfma_f32_16x16x32_bf16(a[1], vf, o[1][nt2], 0, 0, 0);
        }
    }

    // ---- reduce l over the 16 key-lanes ----
    #pragma unroll
    for (int off = 1; off <= 8; off <<= 1)
        #pragma unroll
        for (int mt = 0; mt < 2; mt++)
            #pragma unroll
            for (int i = 0; i < 4; i++)
                l_part[mt][i] += __shfl_xor(l_part[mt][i], off, 64);

    // ---- combine key-half partials in LDS; wave 0 finalizes ----
    __syncthreads();
    float* ox = (float*)lds;              // 96 slots x 64 lanes = 24.6 KB
    float* lx = (float*)(lds + 16384);    // 8 slots x 64 lanes = 2 KB
    if (wave == 1) {
        #pragma unroll
        for (int mt = 0; mt < 2; mt++)
            #pragma unroll
            for (int nt2 = 0; nt2 < 12; nt2++)
                #pragma unroll
                for (int i = 0; i < 4; i++)
                    ox[(((mt * 12 + nt2) * 4 + i) * 64) + lane] = o[mt][nt2][i];
        #pragma unroll
        for (int mt = 0; mt < 2; mt++)
            #pragma unroll
            for (int i = 0; i < 4; i++)
                lx[(mt * 4 + i) * 64 + lane] = l_part[mt][i];
    }
    __syncthreads();
    if (wave == 0) {
        float inv[2][4];
        #pragma unroll
        for (int mt = 0; mt < 2; mt++)
            #pragma unroll
            for (int i = 0; i < 4; i++)
                inv[mt][i] = 1.f / (l_part[mt][i] + lx[(mt * 4 + i) * 64 + lane]);
        #pragma unroll
        for (int mt = 0; mt < 2; mt++)
            #pragma unroll
            for (int nt2 = 0; nt2 < 12; nt2++)
                #pragma unroll
                for (int i = 0; i < 4; i++) {
                    const float v = o[mt][nt2][i] + ox[(((mt * 12 + nt2) * 4 + i) * 64) + lane];
                    const int n = n0 + mt * 16 + quad * 4 + i;
                    attn[((size_t)b * NSEQ + n) * DIMM + h * DVD + nt2 * 16 + l15] =
                        f2bf(v * inv[mt][i]);
                }
    }
}

// ---------------------------------------------------------------------------
extern "C" void kernel_launch(void* const* d_in, const int* in_sizes, int n_in,
                              void* d_out, int out_size, void* d_ws, size_t ws_size,
                              hipStream_t stream)
{
    const float* x   = (const float*)d_in[0];
    const float* Wq  = (const float*)d_in[1];
    const float* Wk  = (const float*)d_in[2];
    const float* Wv  = (const float*)d_in[3];
    const float* Wo  = (const float*)d_in[4];
    const float* bo  = (const float*)d_in[5];
    const float* pos = (const float*)d_in[6];
    const float* rcb = (const float*)d_in[7];
    float* out = (float*)d_out;

    ushortT* xb    = (ushortT*)d_ws;                             // 4096*1536
    ushortT* wqkv  = xb    + (size_t)4096 * DIMM;                // 2560*1536
    ushortT* wo_t  = wqkv  + (size_t)(2 * QCOLS + VCOLS) * DIMM; // 1536*1536
    ushortT* q_ws  = wo_t  + (size_t)DIMM * DIMM;
    ushortT* k_ws  = q_ws  + (size_t)BB * HN * NSEQ * DKD;
    ushortT* v_ws  = k_ws  + (size_t)BB * HN * NSEQ * DKD;       // V^T [b,h,d,slot]
    ushortT* attnb = v_ws  + (size_t)BB * HN * NSEQ * DVD;       // 4096*1536

    prep_kernel<<<dim3(9216), dim3(256), 0, stream>>>(x, Wq, Wk, Wv, Wo, xb, wqkv, wo_t);

    gemm_kernel<<<dim3(40, 32), dim3(256), 0, stream>>>(xb, wqkv, bo, pos, rcb,
                                                        q_ws, k_ws, v_ws, nullptr, 0);
    flash_kernel<<<dim3(1024), dim3(128), 0, stream>>>(q_ws, k_ws, v_ws, attnb);
    gemm_kernel<<<dim3(24, 32), dim3(256), 0, stream>>>(attnb, wo_t, bo, pos, rcb,
                                                        q_ws, k_ws, v_ws, out, 1);
}

// Round 7
// 281.257 us; speedup vs baseline: 1.0496x; 1.0496x over previous
//
#include <hip/hip_runtime.h>

// Problem constants
#define BB    2
#define HN    8
#define NSEQ  2048
#define DIMM  1536
#define DKD   64
#define DVD   192
#define QCOLS 512        // HN*DKD
#define VCOLS 1536       // HN*DVD

typedef short short8 __attribute__((ext_vector_type(8)));
typedef float f32x4  __attribute__((ext_vector_type(4)));
typedef unsigned short ushortT;

static __device__ inline ushortT f2bf(float f) {
    unsigned u = __builtin_bit_cast(unsigned, f);
    u = (u + 0x7FFFu + ((u >> 16) & 1u)) >> 16;
    return (ushortT)u;
}

// async global -> LDS, 16B per lane. LDS dest = wave-uniform base + lane*16.
static __device__ inline void gl_lds16(const ushortT* g, ushortT* l) {
    __builtin_amdgcn_global_load_lds(
        (const __attribute__((address_space(1))) unsigned int*)g,
        (__attribute__((address_space(3))) unsigned int*)l, 16, 0, 0);
}

// HW waitcnt + COMPILER memory fence in one.
#define FENCE_VM0()    asm volatile("s_waitcnt vmcnt(0)" ::: "memory")
#define FENCE_VM12()   asm volatile("s_waitcnt vmcnt(12)" ::: "memory")
#define FENCE_LGKM0()  asm volatile("s_waitcnt lgkmcnt(0)" ::: "memory")
#define FENCE_SOFT()   asm volatile("" ::: "memory")

// ---------------------------------------------------------------------------
// Prep (single launch): region-decoded by blockIdx.x  (unchanged)
// ---------------------------------------------------------------------------
__global__ __launch_bounds__(256)
void prep_kernel(const float* __restrict__ x,
                 const float* __restrict__ Wq, const float* __restrict__ Wk,
                 const float* __restrict__ Wv, const float* __restrict__ Wo,
                 ushortT* __restrict__ xb, ushortT* __restrict__ wqkv,
                 ushortT* __restrict__ wo_t)
{
    __shared__ ushortT tt[32][33];
    const int b = blockIdx.x, tid = threadIdx.x;

    if (b < 3072) {
        const size_t idx = (size_t)b * 256 + tid;
        const float4* p = (const float4*)x + idx * 2;
        const float4 a = p[0], c = p[1];
        short8 v;
        v[0] = f2bf(a.x); v[1] = f2bf(a.y); v[2] = f2bf(a.z); v[3] = f2bf(a.w);
        v[4] = f2bf(c.x); v[5] = f2bf(c.y); v[6] = f2bf(c.z); v[7] = f2bf(c.w);
        *(short8*)(xb + idx * 8) = v;
        return;
    }

    const float* W; ushortT* Wt; int ncols, t;
    if (b < 3840)      { W = Wq; Wt = wqkv;                          ncols = QCOLS; t = b - 3072; }
    else if (b < 4608) { W = Wk; Wt = wqkv + (size_t)QCOLS * DIMM;   ncols = QCOLS; t = b - 3840; }
    else if (b < 6912) { W = Wv; Wt = wqkv + (size_t)2*QCOLS * DIMM; ncols = VCOLS; t = b - 4608; }
    else               { W = Wo; Wt = wo_t;                          ncols = DIMM;  t = b - 6912; }

    const int nbx = ncols >> 5;
    const int c0 = (t % nbx) * 32, k0 = (t / nbx) * 32;
    const int lx = tid & 31, ly = tid >> 5;
    #pragma unroll
    for (int r = 0; r < 4; r++)
        tt[ly + r * 8][lx] = f2bf(W[(size_t)(k0 + ly + r * 8) * ncols + c0 + lx]);
    __syncthreads();
    #pragma unroll
    for (int r = 0; r < 4; r++)
        Wt[(size_t)(c0 + ly + r * 8) * DIMM + k0 + lx] = tt[lx][ly + r * 8];
}

// ---------------------------------------------------------------------------
// GEMM (R7): BM=128, BN=64, BK=64; TWO waves of 64 threads... no — two
// 64-lane waves (block = 128 threads). Wave w computes the 64x64 output
// rows [m0+w*64, +64) x all 64 cols: acc[4][4], 32 MFMA per K-step.
// LDS traffic per K-step per block: A 16 KB (no dup) + B 2x8 KB (2x dup)
// = 32 KB = 256 cyc at 128 B/cyc — balanced against 257 cyc of MFMA
// (vs the old 4-wave layout's 48 KB = 384 cyc, LDS-BW-bound).
// Single-buffered R0 schedule (best measured); proven conflict-free
// BK=64 XOR layout; 24 KB LDS -> 6 blocks/CU.
// v_ws key-slot permutation (R5): key n -> slot 2*(n&15)|((n>>4)&1) within
// each 32-group; matches flash's packed P-store order.
// ---------------------------------------------------------------------------
#define NKT (DIMM / 64)   // 24 K-steps

__global__ __launch_bounds__(128)
void gemm_kernel(const ushortT* __restrict__ A, const ushortT* __restrict__ Bt,
                 const float* __restrict__ bo,
                 const float* __restrict__ pos, const float* __restrict__ rcb,
                 ushortT* __restrict__ q_ws, ushortT* __restrict__ k_ws,
                 ushortT* __restrict__ v_ws, float* __restrict__ Cout, int mode)
{
    __shared__ ushortT As[128 * 64];   // 16 KB
    __shared__ ushortT Bs[64 * 64];    //  8 KB

    const int tid  = threadIdx.x;
    const int wave = tid >> 6, lane = tid & 63;
    const int quad = lane >> 4, l15 = lane & 15;
    const int m0 = blockIdx.y * 128, n0 = blockIdx.x * 64;

    // staging source swizzle: 8 rows x 8 chunks of 8 shorts per gl_lds (1 KB)
    const int sl_r = lane >> 3;
    const int sl_c = ((lane & 7) ^ sl_r) * 8;

    const ushortT* Ab = A  + (size_t)m0 * DIMM;
    const ushortT* Bb = Bt + (size_t)n0 * DIMM;

    f32x4 acc[4][4];
    #pragma unroll
    for (int i = 0; i < 4; i++)
        #pragma unroll
        for (int j = 0; j < 4; j++) acc[i][j] = (f32x4){0.f, 0.f, 0.f, 0.f};

    for (int k0 = 0; k0 < DIMM; k0 += 64) {
        // stage: A 16 groups of 8 rows (8 per wave), B 8 groups (4 per wave)
        #pragma unroll
        for (int t = 0; t < 8; t++) {
            const int g = wave * 8 + t;
            gl_lds16(Ab + (size_t)(g * 8 + sl_r) * DIMM + k0 + sl_c, &As[g * 512]);
        }
        #pragma unroll
        for (int t = 0; t < 4; t++) {
            const int g = wave * 4 + t;
            gl_lds16(Bb + (size_t)(g * 8 + sl_r) * DIMM + k0 + sl_c, &Bs[g * 512]);
        }
        __syncthreads();   // drains vmcnt(0): staged tiles visible

        short8 af[4][2], bf[4][2];
        #pragma unroll
        for (int i = 0; i < 4; i++) {
            const int r = wave * 64 + i * 16 + l15;     // r&7 == l15&7
            #pragma unroll
            for (int ks = 0; ks < 2; ks++)
                af[i][ks] = *(const short8*)&As[r * 64 + (((ks * 4 + quad) ^ (l15 & 7)) * 8)];
        }
        #pragma unroll
        for (int j = 0; j < 4; j++) {
            const int r = j * 16 + l15;
            #pragma unroll
            for (int ks = 0; ks < 2; ks++)
                bf[j][ks] = *(const short8*)&Bs[r * 64 + (((ks * 4 + quad) ^ (l15 & 7)) * 8)];
        }

        #pragma unroll
        for (int ks = 0; ks < 2; ks++)
            #pragma unroll
            for (int i = 0; i < 4; i++)
                #pragma unroll
                for (int j = 0; j < 4; j++)
                    acc[i][j] = __builtin_amdgcn_mfma_f32_16x16x32_bf16(af[i][ks], bf[j][ks], acc[i][j], 0, 0, 0);

        __syncthreads();   // LDS reads retired before next stage overwrites
    }

    #pragma unroll
    for (int i = 0; i < 4; i++) {
        #pragma unroll
        for (int j = 0; j < 4; j++) {
            const int gcol = n0 + j * 16 + l15;
            #pragma unroll
            for (int r = 0; r < 4; r++) {
                const int grow = m0 + wave * 64 + i * 16 + quad * 4 + r;
                const float val = acc[i][j][r];
                if (mode == 1) {
                    Cout[(size_t)grow * DIMM + gcol] = val + bo[gcol];
                } else {
                    const int b = grow >> 11, n = grow & (NSEQ - 1);
                    if (gcol < QCOLS) {
                        const int h = gcol >> 6, d = gcol & 63;
                        q_ws[((size_t)(b * HN + h) * NSEQ + n) * DKD + d] =
                            f2bf(val * 0.125f + pos[((size_t)h * NSEQ + n) * DKD + d] + rcb[h * DKD + d]);
                    } else if (gcol < 2 * QCOLS) {
                        const int c = gcol - QCOLS, h = c >> 6, d = c & 63;
                        k_ws[((size_t)(b * HN + h) * NSEQ + n) * DKD + d] = f2bf(val);
                    } else {
                        const int c = gcol - 2 * QCOLS, h = c / DVD, d = c - h * DVD;
                        // interleaved key-slot within each 32-key group
                        const int p = (n & ~31) | (((n & 15) << 1) | ((n >> 4) & 1));
                        v_ws[((size_t)(b * HN + h) * DVD + d) * NSEQ + p] = f2bf(val);   // [b,h,d,slot]
                    }
                }
            }
        }
    }
}

// ---------------------------------------------------------------------------
// Flash v2c + packed P-store (unchanged from R5).
// Grid 1024 = 16 bh (XCD-affine) x 64 q-tiles of 32 rows. Block = 2 waves.
// Wave w: keys [w*1024, +1024), KT=32, 32 rounds, PRIVATE 16KB K/V staging;
// per-wave self-sync: lgkm0 -> stage K(4)+V(12) -> vmcnt(12) -> QK/softmax/P
// -> vmcnt(0) -> PV. Key-half partials combined via one LDS exchange at end.
// Packed P: lane holds both nt=0/nt=1 values of each P-row; interleaved
// v_ws key slots (2*l15+nt) let them pack into one v_cvt_pk_bf16_f32 +
// one ds_write_b32.
// ---------------------------------------------------------------------------
#define PLD2 40
#define SHIFT 20.0f

__global__ __launch_bounds__(128)
void flash_kernel(const ushortT* __restrict__ q_ws, const ushortT* __restrict__ k_ws,
                  const ushortT* __restrict__ v_ws, ushortT* __restrict__ attn)
{
    // [0,16384): per-wave staging (wave*8192: K 2048 shorts, V 6144 shorts)
    // [16384,18944): P buffers (wave*32*PLD2); reused for l exchange at end
    __shared__ ushortT lds[16384 + 2 * 32 * PLD2];

    const int tid = threadIdx.x;
    const int wave = tid >> 6, lane = tid & 63;
    const int quad = lane >> 4, l15 = lane & 15;

    const int bh = blockIdx.x & 15;        // XCD-affine: bh's blocks share L2
    const int qt = blockIdx.x >> 4;
    const int n0 = qt * 32;
    const int b  = bh >> 3, h = bh & 7;

    const ushortT* kg = k_ws + (size_t)bh * NSEQ * DKD + (size_t)(wave * 1024) * DKD;
    const ushortT* vg = v_ws + (size_t)bh * DVD * NSEQ + wave * 1024;

    ushortT* st = lds + wave * 8192;           // K at [0,2048), V at [2048,8192)
    ushortT* Pw = lds + 16384 + wave * (32 * PLD2);

    // staging source swizzles
    const int k_r = lane >> 3, k_c = ((lane & 7) ^ (k_r & 7)) * 8;   // K: 8 rows x 8 chunks
    const int v_r = lane >> 2, v_c = ((lane & 3) ^ (v_r & 3)) * 8;   // V: 16 rows x 4 chunks

    // Q A-frags (resident): qf[mt][ks], rows n0 + mt*16 + l15
    short8 qf[2][2];
    #pragma unroll
    for (int mt = 0; mt < 2; mt++)
        #pragma unroll
        for (int ks = 0; ks < 2; ks++)
            qf[mt][ks] = *(const short8*)(q_ws + ((size_t)bh * NSEQ + n0 + mt * 16 + l15) * DKD + ks * 32 + quad * 8);

    f32x4 o[2][12];
    #pragma unroll
    for (int mt = 0; mt < 2; mt++)
        #pragma unroll
        for (int nt = 0; nt < 12; nt++) o[mt][nt] = (f32x4){0.f, 0.f, 0.f, 0.f};

    float l_part[2][4];
    #pragma unroll
    for (int mt = 0; mt < 2; mt++)
        #pragma unroll
        for (int i = 0; i < 4; i++) l_part[mt][i] = 0.f;

    for (int kt0 = 0; kt0 < 1024; kt0 += 32) {
        // all prior ds_reads on this wave's buffers must be retired
        FENCE_LGKM0();

        #pragma unroll
        for (int t = 0; t < 4; t++)       // K tile: 32 keys x 64 d = 4 KB
            gl_lds16(kg + (size_t)(kt0 + t * 8 + k_r) * DKD + k_c, st + t * 512);
        #pragma unroll
        for (int u = 0; u < 12; u++)      // V^T tile: 192 d x 32 key-slots = 12 KB
            gl_lds16(vg + (size_t)(u * 16 + v_r) * NSEQ + kt0 + v_c, st + 2048 + u * 512);

        FENCE_VM12();  // 4 oldest (K) landed; V still in flight

        // ---- S = Q @ K^T ----
        f32x4 s[2][2];
        #pragma unroll
        for (int mt = 0; mt < 2; mt++)
            #pragma unroll
            for (int nt = 0; nt < 2; nt++) s[mt][nt] = (f32x4){0.f, 0.f, 0.f, 0.f};
        #pragma unroll
        for (int ks = 0; ks < 2; ks++)
            #pragma unroll
            for (int nt = 0; nt < 2; nt++) {
                const int key = nt * 16 + l15;
                short8 kf = *(const short8*)&st[key * 64 + (((ks * 4 + quad) ^ (key & 7)) * 8)];
                s[0][nt] = __builtin_amdgcn_mfma_f32_16x16x32_bf16(qf[0][ks], kf, s[0][nt], 0, 0, 0);
                s[1][nt] = __builtin_amdgcn_mfma_f32_16x16x32_bf16(qf[1][ks], kf, s[1][nt], 0, 0, 0);
            }

        // ---- p = exp(s - SHIFT); row-sum partials; PACKED P store ----
        // lane holds keys l15 (nt=0) and l15+16 (nt=1) of row mt*16+quad*4+i;
        // interleaved slots (2*l15, 2*l15+1) -> one cvt_pk + one b32 write.
        #pragma unroll
        for (int mt = 0; mt < 2; mt++)
            #pragma unroll
            for (int i = 0; i < 4; i++) {
                const float p0 = __expf(s[mt][0][i] - SHIFT);
                const float p1 = __expf(s[mt][1][i] - SHIFT);
                l_part[mt][i] += p0 + p1;
                unsigned pk;
                asm("v_cvt_pk_bf16_f32 %0, %1, %2" : "=v"(pk) : "v"(p0), "v"(p1));
                *(unsigned*)&Pw[(mt * 16 + quad * 4 + i) * PLD2 + 2 * l15] = pk;
            }

        FENCE_SOFT();  // cross-lane P write->read dep is invisible per-lane

        short8 a[2];
        #pragma unroll
        for (int mt = 0; mt < 2; mt++)
            a[mt] = *(const short8*)&Pw[(mt * 16 + l15) * PLD2 + quad * 8];

        FENCE_VM0();   // V landed

        // ---- O += P @ V (k-slots permuted identically on both operands) ----
        #pragma unroll
        for (int nt2 = 0; nt2 < 12; nt2++) {
            const int d = nt2 * 16 + l15;
            short8 vf = *(const short8*)&st[2048 + d * 32 + ((quad ^ (d & 3)) * 8)];
            o[0][nt2] = __builtin_amdgcn_mfma_f32_16x16x32_bf16(a[0], vf, o[0][nt2], 0, 0, 0);
            o[1][nt2] = __builtin_amdgcn_mfma_f32_16x16x32_bf16(a[1], vf, o[1][nt2], 0, 0, 0);
        }
    }

    // ---- reduce l over the 16 key-lanes ----
    #pragma unroll
    for (int off = 1; off <= 8; off <<= 1)
        #pragma unroll
        for (int mt = 0; mt < 2; mt++)
            #pragma unroll
            for (int i = 0; i < 4; i++)
                l_part[mt][i] += __shfl_xor(l_part[mt][i], off, 64);

    // ---- combine key-half partials in LDS; wave 0 finalizes ----
    __syncthreads();
    float* ox = (float*)lds;              // 96 slots x 64 lanes = 24.6 KB
    float* lx = (float*)(lds + 16384);    // 8 slots x 64 lanes = 2 KB
    if (wave == 1) {
        #pragma unroll
        for (int mt = 0; mt < 2; mt++)
            #pragma unroll
            for (int nt2 = 0; nt2 < 12; nt2++)
                #pragma unroll
                for (int i = 0; i < 4; i++)
                    ox[(((mt * 12 + nt2) * 4 + i) * 64) + lane] = o[mt][nt2][i];
        #pragma unroll
        for (int mt = 0; mt < 2; mt++)
            #pragma unroll
            for (int i = 0; i < 4; i++)
                lx[(mt * 4 + i) * 64 + lane] = l_part[mt][i];
    }
    __syncthreads();
    if (wave == 0) {
        float inv[2][4];
        #pragma unroll
        for (int mt = 0; mt < 2; mt++)
            #pragma unroll
            for (int i = 0; i < 4; i++)
                inv[mt][i] = 1.f / (l_part[mt][i] + lx[(mt * 4 + i) * 64 + lane]);
        #pragma unroll
        for (int mt = 0; mt < 2; mt++)
            #pragma unroll
            for (int nt2 = 0; nt2 < 12; nt2++)
                #pragma unroll
                for (int i = 0; i < 4; i++) {
                    const float v = o[mt][nt2][i] + ox[(((mt * 12 + nt2) * 4 + i) * 64) + lane];
                    const int n = n0 + mt * 16 + quad * 4 + i;
                    attn[((size_t)b * NSEQ + n) * DIMM + h * DVD + nt2 * 16 + l15] =
                        f2bf(v * inv[mt][i]);
                }
    }
}

// ---------------------------------------------------------------------------
extern "C" void kernel_launch(void* const* d_in, const int* in_sizes, int n_in,
                              void* d_out, int out_size, void* d_ws, size_t ws_size,
                              hipStream_t stream)
{
    const float* x   = (const float*)d_in[0];
    const float* Wq  = (const float*)d_in[1];
    const float* Wk  = (const float*)d_in[2];
    const float* Wv  = (const float*)d_in[3];
    const float* Wo  = (const float*)d_in[4];
    const float* bo  = (const float*)d_in[5];
    const float* pos = (const float*)d_in[6];
    const float* rcb = (const float*)d_in[7];
    float* out = (float*)d_out;

    ushortT* xb    = (ushortT*)d_ws;                             // 4096*1536
    ushortT* wqkv  = xb    + (size_t)4096 * DIMM;                // 2560*1536
    ushortT* wo_t  = wqkv  + (size_t)(2 * QCOLS + VCOLS) * DIMM; // 1536*1536
    ushortT* q_ws  = wo_t  + (size_t)DIMM * DIMM;
    ushortT* k_ws  = q_ws  + (size_t)BB * HN * NSEQ * DKD;
    ushortT* v_ws  = k_ws  + (size_t)BB * HN * NSEQ * DKD;       // V^T [b,h,d,slot]
    ushortT* attnb = v_ws  + (size_t)BB * HN * NSEQ * DVD;       // 4096*1536

    prep_kernel<<<dim3(9216), dim3(256), 0, stream>>>(x, Wq, Wk, Wv, Wo, xb, wqkv, wo_t);

    gemm_kernel<<<dim3(40, 32), dim3(128), 0, stream>>>(xb, wqkv, bo, pos, rcb,
                                                        q_ws, k_ws, v_ws, nullptr, 0);
    flash_kernel<<<dim3(1024), dim3(128), 0, stream>>>(q_ws, k_ws, v_ws, attnb);
    gemm_kernel<<<dim3(24, 32), dim3(128), 0, stream>>>(attnb, wo_t, bo, pos, rcb,
                                                        q_ws, k_ws, v_ws, out, 1);
}

// Round 8
// 260.299 us; speedup vs baseline: 1.1341x; 1.0805x over previous
//
#include <hip/hip_runtime.h>

// Problem constants
#define BB    2
#define HN    8
#define NSEQ  2048
#define DIMM  1536
#define DKD   64
#define DVD   192
#define QCOLS 512        // HN*DKD
#define VCOLS 1536       // HN*DVD

typedef short short8 __attribute__((ext_vector_type(8)));
typedef float f32x4  __attribute__((ext_vector_type(4)));
typedef unsigned short ushortT;

static __device__ inline ushortT f2bf(float f) {
    unsigned u = __builtin_bit_cast(unsigned, f);
    u = (u + 0x7FFFu + ((u >> 16) & 1u)) >> 16;
    return (ushortT)u;
}

// async global -> LDS, 16B per lane. LDS dest = wave-uniform base + lane*16.
static __device__ inline void gl_lds16(const ushortT* g, ushortT* l) {
    __builtin_amdgcn_global_load_lds(
        (const __attribute__((address_space(1))) unsigned int*)g,
        (__attribute__((address_space(3))) unsigned int*)l, 16, 0, 0);
}

// HW waitcnt + COMPILER memory fence in one.
#define FENCE_VM0()    asm volatile("s_waitcnt vmcnt(0)" ::: "memory")
#define FENCE_VM12()   asm volatile("s_waitcnt vmcnt(12)" ::: "memory")
#define FENCE_LGKM0()  asm volatile("s_waitcnt lgkmcnt(0)" ::: "memory")
#define FENCE_SOFT()   asm volatile("" ::: "memory")

// ---------------------------------------------------------------------------
// Prep (single launch): region-decoded by blockIdx.x  (unchanged)
// ---------------------------------------------------------------------------
__global__ __launch_bounds__(256)
void prep_kernel(const float* __restrict__ x,
                 const float* __restrict__ Wq, const float* __restrict__ Wk,
                 const float* __restrict__ Wv, const float* __restrict__ Wo,
                 ushortT* __restrict__ xb, ushortT* __restrict__ wqkv,
                 ushortT* __restrict__ wo_t)
{
    __shared__ ushortT tt[32][33];
    const int b = blockIdx.x, tid = threadIdx.x;

    if (b < 3072) {
        const size_t idx = (size_t)b * 256 + tid;
        const float4* p = (const float4*)x + idx * 2;
        const float4 a = p[0], c = p[1];
        short8 v;
        v[0] = f2bf(a.x); v[1] = f2bf(a.y); v[2] = f2bf(a.z); v[3] = f2bf(a.w);
        v[4] = f2bf(c.x); v[5] = f2bf(c.y); v[6] = f2bf(c.z); v[7] = f2bf(c.w);
        *(short8*)(xb + idx * 8) = v;
        return;
    }

    const float* W; ushortT* Wt; int ncols, t;
    if (b < 3840)      { W = Wq; Wt = wqkv;                          ncols = QCOLS; t = b - 3072; }
    else if (b < 4608) { W = Wk; Wt = wqkv + (size_t)QCOLS * DIMM;   ncols = QCOLS; t = b - 3840; }
    else if (b < 6912) { W = Wv; Wt = wqkv + (size_t)2*QCOLS * DIMM; ncols = VCOLS; t = b - 4608; }
    else               { W = Wo; Wt = wo_t;                          ncols = DIMM;  t = b - 6912; }

    const int nbx = ncols >> 5;
    const int c0 = (t % nbx) * 32, k0 = (t / nbx) * 32;
    const int lx = tid & 31, ly = tid >> 5;
    #pragma unroll
    for (int r = 0; r < 4; r++)
        tt[ly + r * 8][lx] = f2bf(W[(size_t)(k0 + ly + r * 8) * ncols + c0 + lx]);
    __syncthreads();
    #pragma unroll
    for (int r = 0; r < 4; r++)
        Wt[(size_t)(c0 + ly + r * 8) * DIMM + k0 + lx] = tt[lx][ly + r * 8];
}

// ---------------------------------------------------------------------------
// GEMM (R8 = R0 restored): BM=128, BN=64, BK=64; 4 waves, each 32x64 out,
// acc[2][4]; single-buffered, 2 barriers per K-step. Best-measured gemm
// (83.4 us; four alternative schedules R1/R2/R6/R7 all 85-96). LDS 24 KB.
// v_ws key-slot permutation (R5): key n -> slot 2*(n&15)|((n>>4)&1) within
// each 32-key group; matches flash's packed P-store order.
// ---------------------------------------------------------------------------
__global__ __launch_bounds__(256)
void gemm_kernel(const ushortT* __restrict__ A, const ushortT* __restrict__ Bt,
                 const float* __restrict__ bo,
                 const float* __restrict__ pos, const float* __restrict__ rcb,
                 ushortT* __restrict__ q_ws, ushortT* __restrict__ k_ws,
                 ushortT* __restrict__ v_ws, float* __restrict__ Cout, int mode)
{
    __shared__ ushortT As[128 * 64];   // 16 KB
    __shared__ ushortT Bs[64 * 64];    //  8 KB

    const int tid  = threadIdx.x;
    const int wave = tid >> 6, lane = tid & 63;
    const int quad = lane >> 4, l15 = lane & 15;
    const int m0 = blockIdx.y * 128, n0 = blockIdx.x * 64;

    const int sl_r = lane >> 3;
    const int sl_c = ((lane & 7) ^ sl_r) * 8;

    const ushortT* Ab = A  + (size_t)m0 * DIMM;
    const ushortT* Bb = Bt + (size_t)n0 * DIMM;

    f32x4 acc[2][4];
    #pragma unroll
    for (int i = 0; i < 2; i++)
        #pragma unroll
        for (int j = 0; j < 4; j++) acc[i][j] = (f32x4){0.f, 0.f, 0.f, 0.f};

    for (int k0 = 0; k0 < DIMM; k0 += 64) {
        #pragma unroll
        for (int t = 0; t < 4; t++) {
            const int g = wave * 4 + t;
            gl_lds16(Ab + (size_t)(g * 8 + sl_r) * DIMM + k0 + sl_c, &As[g * 512]);
        }
        #pragma unroll
        for (int t = 0; t < 2; t++) {
            const int g = wave * 2 + t;
            gl_lds16(Bb + (size_t)(g * 8 + sl_r) * DIMM + k0 + sl_c, &Bs[g * 512]);
        }
        __syncthreads();

        short8 af[2][2], bf[4][2];
        #pragma unroll
        for (int i = 0; i < 2; i++) {
            const int r = wave * 32 + i * 16 + l15;
            #pragma unroll
            for (int ks = 0; ks < 2; ks++)
                af[i][ks] = *(const short8*)&As[r * 64 + (((ks * 4 + quad) ^ (l15 & 7)) * 8)];
        }
        #pragma unroll
        for (int j = 0; j < 4; j++) {
            const int r = j * 16 + l15;
            #pragma unroll
            for (int ks = 0; ks < 2; ks++)
                bf[j][ks] = *(const short8*)&Bs[r * 64 + (((ks * 4 + quad) ^ (l15 & 7)) * 8)];
        }

        #pragma unroll
        for (int ks = 0; ks < 2; ks++)
            #pragma unroll
            for (int i = 0; i < 2; i++)
                #pragma unroll
                for (int j = 0; j < 4; j++)
                    acc[i][j] = __builtin_amdgcn_mfma_f32_16x16x32_bf16(af[i][ks], bf[j][ks], acc[i][j], 0, 0, 0);

        __syncthreads();
    }

    #pragma unroll
    for (int i = 0; i < 2; i++) {
        #pragma unroll
        for (int j = 0; j < 4; j++) {
            const int gcol = n0 + j * 16 + l15;
            #pragma unroll
            for (int r = 0; r < 4; r++) {
                const int grow = m0 + wave * 32 + i * 16 + quad * 4 + r;
                const float val = acc[i][j][r];
                if (mode == 1) {
                    Cout[(size_t)grow * DIMM + gcol] = val + bo[gcol];
                } else {
                    const int b = grow >> 11, n = grow & (NSEQ - 1);
                    if (gcol < QCOLS) {
                        const int h = gcol >> 6, d = gcol & 63;
                        q_ws[((size_t)(b * HN + h) * NSEQ + n) * DKD + d] =
                            f2bf(val * 0.125f + pos[((size_t)h * NSEQ + n) * DKD + d] + rcb[h * DKD + d]);
                    } else if (gcol < 2 * QCOLS) {
                        const int c = gcol - QCOLS, h = c >> 6, d = c & 63;
                        k_ws[((size_t)(b * HN + h) * NSEQ + n) * DKD + d] = f2bf(val);
                    } else {
                        const int c = gcol - 2 * QCOLS, h = c / DVD, d = c - h * DVD;
                        // interleaved key-slot within each 32-key group
                        const int p = (n & ~31) | (((n & 15) << 1) | ((n >> 4) & 1));
                        v_ws[((size_t)(b * HN + h) * DVD + d) * NSEQ + p] = f2bf(val);   // [b,h,d,slot]
                    }
                }
            }
        }
    }
}

// ---------------------------------------------------------------------------
// Flash v2c + packed P-store (R5) + V-SWIZZLE FIX.
// Grid 1024 = 16 bh (XCD-affine) x 64 q-tiles of 32 rows. Block = 2 waves.
// Wave w: keys [w*1024, +1024), KT=32, 32 rounds, PRIVATE 16KB K/V staging;
// per-wave self-sync: lgkm0 -> stage K(4)+V(12) -> vmcnt(12) -> QK/softmax/P
// -> vmcnt(0) -> PV. Key-half partials combined via one LDS exchange at end.
// V-swizzle fix: V^T rows are 64 B, so rows d and d+2 share the same bank
// set; the old chunk-swizzle quad^(d&3) left lanes {d,d+4,d+8,d+12} on the
// same 4 banks -> 4-way conflict on every PV ds_read_b128 (= the measured
// 3.67M SQ_LDS_BANK_CONFLICT: 12 reads x ~4.7 cyc x 1024blk x 2w x 32rds).
// New swizzle (d>>1)&3 gives each bank-parity group of 8 lanes all four
// 16-B slots 2x each -> 2-way = free (m136). Applied BOTH sides (store
// source v_c and read), same involution (rule #21).
// ---------------------------------------------------------------------------
#define PLD2 40
#define SHIFT 20.0f

__global__ __launch_bounds__(128)
void flash_kernel(const ushortT* __restrict__ q_ws, const ushortT* __restrict__ k_ws,
                  const ushortT* __restrict__ v_ws, ushortT* __restrict__ attn)
{
    // [0,16384): per-wave staging (wave*8192: K 2048 shorts, V 6144 shorts)
    // [16384,18944): P buffers (wave*32*PLD2); reused for l exchange at end
    __shared__ ushortT lds[16384 + 2 * 32 * PLD2];

    const int tid = threadIdx.x;
    const int wave = tid >> 6, lane = tid & 63;
    const int quad = lane >> 4, l15 = lane & 15;

    const int bh = blockIdx.x & 15;        // XCD-affine: bh's blocks share L2
    const int qt = blockIdx.x >> 4;
    const int n0 = qt * 32;
    const int b  = bh >> 3, h = bh & 7;

    const ushortT* kg = k_ws + (size_t)bh * NSEQ * DKD + (size_t)(wave * 1024) * DKD;
    const ushortT* vg = v_ws + (size_t)bh * DVD * NSEQ + wave * 1024;

    ushortT* st = lds + wave * 8192;           // K at [0,2048), V at [2048,8192)
    ushortT* Pw = lds + 16384 + wave * (32 * PLD2);

    // staging source swizzles
    const int k_r = lane >> 3, k_c = ((lane & 7) ^ (k_r & 7)) * 8;        // K: 8 rows x 8 chunks
    const int v_r = lane >> 2;
    const int v_c = ((lane & 3) ^ ((v_r >> 1) & 3)) * 8;                  // V: 16 rows x 4 chunks, (row>>1) swizzle

    // Q A-frags (resident): qf[mt][ks], rows n0 + mt*16 + l15
    short8 qf[2][2];
    #pragma unroll
    for (int mt = 0; mt < 2; mt++)
        #pragma unroll
        for (int ks = 0; ks < 2; ks++)
            qf[mt][ks] = *(const short8*)(q_ws + ((size_t)bh * NSEQ + n0 + mt * 16 + l15) * DKD + ks * 32 + quad * 8);

    f32x4 o[2][12];
    #pragma unroll
    for (int mt = 0; mt < 2; mt++)
        #pragma unroll
        for (int nt = 0; nt < 12; nt++) o[mt][nt] = (f32x4){0.f, 0.f, 0.f, 0.f};

    float l_part[2][4];
    #pragma unroll
    for (int mt = 0; mt < 2; mt++)
        #pragma unroll
        for (int i = 0; i < 4; i++) l_part[mt][i] = 0.f;

    for (int kt0 = 0; kt0 < 1024; kt0 += 32) {
        // all prior ds_reads on this wave's buffers must be retired
        FENCE_LGKM0();

        #pragma unroll
        for (int t = 0; t < 4; t++)       // K tile: 32 keys x 64 d = 4 KB
            gl_lds16(kg + (size_t)(kt0 + t * 8 + k_r) * DKD + k_c, st + t * 512);
        #pragma unroll
        for (int u = 0; u < 12; u++)      // V^T tile: 192 d x 32 key-slots = 12 KB
            gl_lds16(vg + (size_t)(u * 16 + v_r) * NSEQ + kt0 + v_c, st + 2048 + u * 512);

        FENCE_VM12();  // 4 oldest (K) landed; V still in flight

        // ---- S = Q @ K^T ----
        f32x4 s[2][2];
        #pragma unroll
        for (int mt = 0; mt < 2; mt++)
            #pragma unroll
            for (int nt = 0; nt < 2; nt++) s[mt][nt] = (f32x4){0.f, 0.f, 0.f, 0.f};
        #pragma unroll
        for (int ks = 0; ks < 2; ks++)
            #pragma unroll
            for (int nt = 0; nt < 2; nt++) {
                const int key = nt * 16 + l15;
                short8 kf = *(const short8*)&st[key * 64 + (((ks * 4 + quad) ^ (key & 7)) * 8)];
                s[0][nt] = __builtin_amdgcn_mfma_f32_16x16x32_bf16(qf[0][ks], kf, s[0][nt], 0, 0, 0);
                s[1][nt] = __builtin_amdgcn_mfma_f32_16x16x32_bf16(qf[1][ks], kf, s[1][nt], 0, 0, 0);
            }

        // ---- p = exp(s - SHIFT); row-sum partials; PACKED P store ----
        // lane holds keys l15 (nt=0) and l15+16 (nt=1) of row mt*16+quad*4+i;
        // interleaved slots (2*l15, 2*l15+1) -> one cvt_pk + one b32 write.
        #pragma unroll
        for (int mt = 0; mt < 2; mt++)
            #pragma unroll
            for (int i = 0; i < 4; i++) {
                const float p0 = __expf(s[mt][0][i] - SHIFT);
                const float p1 = __expf(s[mt][1][i] - SHIFT);
                l_part[mt][i] += p0 + p1;
                unsigned pk;
                asm("v_cvt_pk_bf16_f32 %0, %1, %2" : "=v"(pk) : "v"(p0), "v"(p1));
                *(unsigned*)&Pw[(mt * 16 + quad * 4 + i) * PLD2 + 2 * l15] = pk;
            }

        FENCE_SOFT();  // cross-lane P write->read dep is invisible per-lane

        short8 a[2];
        #pragma unroll
        for (int mt = 0; mt < 2; mt++)
            a[mt] = *(const short8*)&Pw[(mt * 16 + l15) * PLD2 + quad * 8];

        FENCE_VM0();   // V landed

        // ---- O += P @ V (k-slots permuted identically on both operands) ----
        #pragma unroll
        for (int nt2 = 0; nt2 < 12; nt2++) {
            const int d = nt2 * 16 + l15;
            short8 vf = *(const short8*)&st[2048 + d * 32 + ((quad ^ ((l15 >> 1) & 3)) * 8)];
            o[0][nt2] = __builtin_amdgcn_mfma_f32_16x16x32_bf16(a[0], vf, o[0][nt2], 0, 0, 0);
            o[1][nt2] = __builtin_amdgcn_mfma_f32_16x16x32_bf16(a[1], vf, o[1][nt2], 0, 0, 0);
        }
    }

    // ---- reduce l over the 16 key-lanes ----
    #pragma unroll
    for (int off = 1; off <= 8; off <<= 1)
        #pragma unroll
        for (int mt = 0; mt < 2; mt++)
            #pragma unroll
            for (int i = 0; i < 4; i++)
                l_part[mt][i] += __shfl_xor(l_part[mt][i], off, 64);

    // ---- combine key-half partials in LDS; wave 0 finalizes ----
    __syncthreads();
    float* ox = (float*)lds;              // 96 slots x 64 lanes = 24.6 KB
    float* lx = (float*)(lds + 16384);    // 8 slots x 64 lanes = 2 KB
    if (wave == 1) {
        #pragma unroll
        for (int mt = 0; mt < 2; mt++)
            #pragma unroll
            for (int nt2 = 0; nt2 < 12; nt2++)
                #pragma unroll
                for (int i = 0; i < 4; i++)
                    ox[(((mt * 12 + nt2) * 4 + i) * 64) + lane] = o[mt][nt2][i];
        #pragma unroll
        for (int mt = 0; mt < 2; mt++)
            #pragma unroll
            for (int i = 0; i < 4; i++)
                lx[(mt * 4 + i) * 64 + lane] = l_part[mt][i];
    }
    __syncthreads();
    if (wave == 0) {
        float inv[2][4];
        #pragma unroll
        for (int mt = 0; mt < 2; mt++)
            #pragma unroll
            for (int i = 0; i < 4; i++)
                inv[mt][i] = 1.f / (l_part[mt][i] + lx[(mt * 4 + i) * 64 + lane]);
        #pragma unroll
        for (int mt = 0; mt < 2; mt++)
            #pragma unroll
            for (int nt2 = 0; nt2 < 12; nt2++)
                #pragma unroll
                for (int i = 0; i < 4; i++) {
                    const float v = o[mt][nt2][i] + ox[(((mt * 12 + nt2) * 4 + i) * 64) + lane];
                    const int n = n0 + mt * 16 + quad * 4 + i;
                    attn[((size_t)b * NSEQ + n) * DIMM + h * DVD + nt2 * 16 + l15] =
                        f2bf(v * inv[mt][i]);
                }
    }
}

// ---------------------------------------------------------------------------
extern "C" void kernel_launch(void* const* d_in, const int* in_sizes, int n_in,
                              void* d_out, int out_size, void* d_ws, size_t ws_size,
                              hipStream_t stream)
{
    const float* x   = (const float*)d_in[0];
    const float* Wq  = (const float*)d_in[1];
    const float* Wk  = (const float*)d_in[2];
    const float* Wv  = (const float*)d_in[3];
    const float* Wo  = (const float*)d_in[4];
    const float* bo  = (const float*)d_in[5];
    const float* pos = (const float*)d_in[6];
    const float* rcb = (const float*)d_in[7];
    float* out = (float*)d_out;

    ushortT* xb    = (ushortT*)d_ws;                             // 4096*1536
    ushortT* wqkv  = xb    + (size_t)4096 * DIMM;                // 2560*1536
    ushortT* wo_t  = wqkv  + (size_t)(2 * QCOLS + VCOLS) * DIMM; // 1536*1536
    ushortT* q_ws  = wo_t  + (size_t)DIMM * DIMM;
    ushortT* k_ws  = q_ws  + (size_t)BB * HN * NSEQ * DKD;
    ushortT* v_ws  = k_ws  + (size_t)BB * HN * NSEQ * DKD;       // V^T [b,h,d,slot]
    ushortT* attnb = v_ws  + (size_t)BB * HN * NSEQ * DVD;       // 4096*1536

    prep_kernel<<<dim3(9216), dim3(256), 0, stream>>>(x, Wq, Wk, Wv, Wo, xb, wqkv, wo_t);

    gemm_kernel<<<dim3(40, 32), dim3(256), 0, stream>>>(xb, wqkv, bo, pos, rcb,
                                                        q_ws, k_ws, v_ws, nullptr, 0);
    flash_kernel<<<dim3(1024), dim3(128), 0, stream>>>(q_ws, k_ws, v_ws, attnb);
    gemm_kernel<<<dim3(24, 32), dim3(256), 0, stream>>>(attnb, wo_t, bo, pos, rcb,
                                                        q_ws, k_ws, v_ws, out, 1);
}